// Round 4
// baseline (165.129 us; speedup 1.0000x reference)
//
#include <hip/hip_runtime.h>
#include <hip/hip_bf16.h>
#include <math.h>

// Problem constants (reference: B=8, H=W=512)
#define Bsz    8
#define Wdim   512
#define HWv    (512 * 512)       // 262144 = 2^18
#define LOG2HW 18
#define NIMG   16                // {bg(0..7), fg(8..15)}
#define TW     64                // tile width  (one wave row)
#define TH     32                // tile height (halved critical path)
#define TPIX   (TW * TH)         // 2048 px per tile
#define NTILE  (NIMG * 128)      // 2048 (img, tile) pairs: 8 cols x 16 strips
#define LCAP   1024              // max roots per 64x32 tile (checkerboard)
#define CEBLK  3072              // k_ce blocks: 3 preds * 8 b * 128 blocks
#define CNTBLK 1024              // k_ce blocks with p==0 (count producers)
#define NBORD  704               // k_border blocks: 16*22*512/256

// ws layout (int32 units):
//   [0, NIMG*HWv)            labels: pixel -> tile root (global idx) or -1;
//                            tile-root slots -> final root after k_flat2
//   [NIMG*HWv, 2*NIMG*HWv)   areasF: zeroed at root slots (k_local pass 4),
//                            final roots accumulate totals in k_flat2
//   [2*NIMG*HWv, +16)        per-image max area
//   then (8-byte aligned):   double sums[2]; int counts[2] (legacy pad)
//   then: u64 bitsBG[8*4096]; u64 bitsFG[8*4096]   (keep-verdict bitmasks)
//   then: float pf[CEBLK]; float pbg[CEBLK]; int pcf[CNTBLK]; int pcb[CNTBLK]
//   then: int rootlist[NTILE*LCAP]  (packed (area<<12)|inTileIdx)
//   then: int rootcnt[NTILE]

// ---------------- union-find (atomicMin only: parents monotone decreasing,
// links point to smaller index => lock-free correct). ----------------
__device__ __forceinline__ int uf_find(int* L, int x) {
  int p = L[x];
  while (p != x) {
    int gp = L[p];
    if (gp != p) atomicMin(&L[x], gp);  // grandparent compression (monotone)
    x = gp;
    p = L[x];
  }
  return x;
}

// Read-only find: no compression writes.
__device__ __forceinline__ int find_ro(const int* __restrict__ L, int x) {
  int p = L[x];
  while (p != x) { x = p; p = L[x]; }
  return x;
}

__device__ __forceinline__ void uf_union(int* L, int a, int b) {
  a = uf_find(L, a);
  b = uf_find(L, b);
  while (a != b) {
    if (a < b) { int t = a; a = b; b = t; }  // ensure a > b
    int old = atomicMin(&L[a], b);
    if (old == a) return;  // linked a -> b
    a = old;               // parent already lowered; keep merging
  }
}

// ---------------- kernels ----------------

// Per-tile CCL in LDS, run-based: a wave == one 64-px row. 64x32 tiles:
// 2048 px/block -> per-block serial critical path HALVED vs 64x64; 2048
// blocks x 256 thr = 8 blocks/CU (32 waves) -> whole grid resident in one
// batch. Emits labels + compact per-tile root list (wave-aggregated append)
// + zeroes areasF at root slots + inits maxa (block 0).
__global__ __launch_bounds__(256, 8) void k_local(const float* __restrict__ cams,
                                                  int* __restrict__ labels,
                                                  int* __restrict__ areasF,
                                                  int* __restrict__ maxa,
                                                  int* __restrict__ rootlist,
                                                  int* __restrict__ rootcnt) {
  int img  = blockIdx.x >> 7;          // 0..15
  int tile = blockIdx.x & 127;         // 8 cols x 16 strips
  int tS = tile >> 3, tX = tile & 7;
  int b = img & 7;
  bool fg = (img & 8) != 0;
  int gbase = img << LOG2HW;
  int oy = tS * TH, ox = tX * TW;
  int lane = threadIdx.x & 63;

  __shared__ int P[TPIX];              // parents, 8 KB
  __shared__ int A[TPIX];              // local areas, 8 KB
  __shared__ int lcount;
  if (threadIdx.x == 0) lcount = 0;
  if (blockIdx.x == 0 && threadIdx.x < NIMG) maxa[threadIdx.x] = 0;

  // pass 1: mask load + per-row run-start init (wave covers exactly one row)
  #pragma unroll
  for (int it = 0; it < 8; ++it) {
    int i  = it * 256 + threadIdx.x;   // i & 63 == lane
    int ly = i >> 6;                   // 0..31
    float c = cams[(b << LOG2HW) + ((oy + ly) << 9) + (ox + lane)];
    bool m = fg ? (c > 0.6f) : (c >= 0.2f);
    unsigned long long bm = __ballot(m);
    int par = -1;
    if (m) {
      unsigned long long below = (1ULL << lane) - 1ULL;
      unsigned long long z = (~bm) & below;       // zeros below this lane
      int rs = z ? (64 - __clzll(z)) : 0;          // run start = highest zero + 1
      par = (ly << 6) + rs;
    }
    P[i] = par;
    A[i] = 0;
  }
  __syncthreads();

  // pass 2: vertical unions, one per overlap segment (dedup via west pair)
  #pragma unroll
  for (int it = 0; it < 8; ++it) {
    int i = it * 256 + threadIdx.x;
    if (i >= TW && P[i] >= 0 && P[i - TW] >= 0) {
      bool skip = (lane > 0) && (P[i - 1] >= 0) && (P[i - TW - 1] >= 0);
      if (!skip) uf_union(P, i, i - TW);
    }
  }
  __syncthreads();

  // pass 3: PER-RUN find + shuffle broadcast + per-run area add.
  #pragma unroll
  for (int it = 0; it < 8; ++it) {
    int i = it * 256 + threadIdx.x;
    bool m = P[i] >= 0;
    unsigned long long bm = __ballot(m);
    int rs = 0;
    if (m) {
      unsigned long long below = (1ULL << lane) - 1ULL;
      unsigned long long z = (~bm) & below;
      rs = z ? (64 - __clzll(z)) : 0;
    }
    bool isStart = m && (rs == lane);
    int r = -1;
    if (isStart) r = find_ro(P, i);
    int root = __shfl(r, rs);          // valid wherever m
    if (m) P[i] = root;
    if (isStart) {
      unsigned long long t = (~bm) >> lane;
      int runlen = t ? (__ffsll((long long)t) - 1) : (64 - lane);
      atomicAdd(&A[root], runlen);
    }
  }
  __syncthreads();

  // pass 4: labels write + wave-aggregated root-list append + areasF zero
  int lbase = blockIdx.x << 10;        // LCAP entries per tile
  #pragma unroll
  for (int it = 0; it < 8; ++it) {
    int i  = it * 256 + threadIdx.x;
    int ly = i >> 6;
    int g  = ((oy + ly) << 9) + (ox + lane);
    int p  = P[i];
    int lab = -1;
    if (p >= 0) lab = ((oy + (p >> 6)) << 9) + (ox + (p & 63));
    labels[gbase + g] = lab;
    bool isRoot = (p == i);            // p==-1 never equals i>=0
    unsigned long long bm = __ballot(isRoot);
    int nr = __popcll(bm);
    int basepos = 0;
    if (lane == 0 && nr) basepos = atomicAdd(&lcount, nr);
    basepos = __shfl(basepos, 0);
    if (isRoot) {
      int off = (int)__popcll(bm & ((1ULL << lane) - 1ULL));
      rootlist[lbase + basepos + off] = (A[i] << 12) | i;
      areasF[gbase + g] = 0;           // sparse zero (fill poisons ws)
    }
  }
  __syncthreads();
  if (threadIdx.x == 0) rootcnt[blockIdx.x] = lcount;
}

// Merge across tile boundaries, one union per contiguous overlap segment.
// Seams per image: 7 vertical (x=64k+63) + 15 horizontal (y=32h+31).
__global__ void k_border(int* __restrict__ labels) {
  const int per_img = 22 * Wdim;       // 11264
  int t = blockIdx.x * blockDim.x + threadIdx.x;
  if (t >= NIMG * per_img) return;
  int img = t / per_img;
  int r   = t - img * per_img;
  int k = r >> 9, j = r & (Wdim - 1);
  int* L = labels + (img << LOG2HW);
  // mask-ness (>=0 vs -1) of label slots is immutable here => dedup stable.
  if (k < 7) {                          // vertical border: x = 64k+63, union east
    int x = TW * k + (TW - 1);
    int p = (j << 9) + x, q = p + 1;    // j = y
    if (L[p] >= 0 && L[q] >= 0) {
      bool skip = (j > 0) && (L[p - Wdim] >= 0) && (L[q - Wdim] >= 0);
      if (!skip) uf_union(L, p, q);
    }
  } else {                              // horizontal border: y = 32h+31, union south
    int y = TH * (k - 7) + (TH - 1);
    int p = (y << 9) + j, q = p + Wdim; // j = x
    if (L[p] >= 0 && L[q] >= 0) {
      bool skip = (j > 0) && (L[p - 1] >= 0) && (L[q - 1] >= 0);
      if (!skip) uf_union(L, p, q);
    }
  }
}

// List-driven flatten + area push + RUNNING max: every component's final
// total is observed by its LAST adder (prev+area), and all intermediate
// values are <= total, so max over (prev+area) == max over totals.
__global__ __launch_bounds__(256) void k_flat2(int* __restrict__ labels,
                                               const int* __restrict__ rootlist,
                                               const int* __restrict__ rootcnt,
                                               int* __restrict__ areasF,
                                               int* __restrict__ maxa) {
  int tileg = blockIdx.x;              // 0..2047
  int img  = tileg >> 7;
  int tile = tileg & 127;
  int tS = tile >> 3, tX = tile & 7;
  int oy = tS * TH, ox = tX * TW;
  int cnt = rootcnt[tileg];
  int lbase = tileg << 10;
  int* L = labels + (img << LOG2HW);
  int* AF = areasF + (img << LOG2HW);
  int mymax = 0;
  for (int e = threadIdx.x; e < cnt; e += 256) {
    int ent  = rootlist[lbase + e];
    int i    = ent & 4095;
    int area = ent >> 12;
    int g = ((oy + (i >> 6)) << 9) + (ox + (i & 63));
    int fr = find_ro(L, g);
    L[g] = fr;                          // own slot -> final root (monotone-safe)
    int prev = atomicAdd(&AF[fr], area);
    mymax = max(mymax, prev + area);
  }
  #pragma unroll
  for (int off = 32; off > 0; off >>= 1)
    mymax = max(mymax, __shfl_down(mymax, off));
  __shared__ int lm[4];
  int wave = threadIdx.x >> 6;
  if ((threadIdx.x & 63) == 0) lm[wave] = mymax;
  __syncthreads();
  if (threadIdx.x == 0) {
    int bm = max(max(lm[0], lm[1]), max(lm[2], lm[3]));
    if (bm > 0) atomicMax(&maxa[img], bm);
  }
}

// Fused verdict + bit pack, one block per tile: list-driven LDS verdict
// table (labels always point to IN-TILE roots), then per-pixel LDS lookup
// and 64-px u64 bit packing. Replaces k_verd_root + k_vbits.
__global__ __launch_bounds__(256) void k_vmerge(const int* __restrict__ labels,
                                                const int* __restrict__ rootlist,
                                                const int* __restrict__ rootcnt,
                                                const int* __restrict__ areasF,
                                                const int* __restrict__ maxa,
                                                unsigned long long* __restrict__ bitsBG,
                                                unsigned long long* __restrict__ bitsFG) {
  int tileg = blockIdx.x;
  int img  = tileg >> 7;
  int tile = tileg & 127;
  int tS = tile >> 3, tX = tile & 7;
  int oy = tS * TH, ox = tX * TW;
  int cnt = rootcnt[tileg];
  int lbase = tileg << 10;
  int mx = maxa[img];
  const int* L  = labels + (img << LOG2HW);
  const int* AF = areasF + (img << LOG2HW);

  __shared__ unsigned char V[TPIX];    // per-root verdict, 2 KB
  for (int e = threadIdx.x; e < cnt; e += 256) {
    int i = rootlist[lbase + e] & 4095;
    int g = ((oy + (i >> 6)) << 9) + (ox + (i & 63));
    V[i] = (2 * AF[L[g]] > mx) ? 1 : 0;   // L[g] = final root (k_flat2)
  }
  __syncthreads();

  unsigned long long* dst = (img < 8) ? (bitsBG + ((img & 7) << 12))
                                      : (bitsFG + ((img & 7) << 12));
  #pragma unroll
  for (int it = 0; it < 2; ++it) {
    int grp = it * 256 + threadIdx.x;  // 0..511 (4-px groups), 16 per row
    int row = grp >> 4;                // 0..31
    int4 lb = *(const int4*)&L[((oy + row) << 9) + ox + ((grp & 15) << 2)];
    unsigned nib = 0;
    if (lb.x >= 0) nib |= (unsigned)V[(((lb.x >> 9) & 31) << 6) | (lb.x & 63)];
    if (lb.y >= 0) nib |= (unsigned)V[(((lb.y >> 9) & 31) << 6) | (lb.y & 63)] << 1;
    if (lb.z >= 0) nib |= (unsigned)V[(((lb.z >> 9) & 31) << 6) | (lb.z & 63)] << 2;
    if (lb.w >= 0) nib |= (unsigned)V[(((lb.w >> 9) & 31) << 6) | (lb.w & 63)] << 3;
    unsigned long long w = (unsigned long long)nib << ((grp & 15) << 2);
    w |= __shfl_xor(w, 1);
    w |= __shfl_xor(w, 2);
    w |= __shfl_xor(w, 4);
    w |= __shfl_xor(w, 8);
    if ((threadIdx.x & 15) == 0) dst[((oy + row) << 3) + tX] = w;
  }
}

// Pure-streaming CE, one thread per (p, b, 8-px group): 4 float4 loads + 1
// cached u64 bit-byte per side, 2x ILP vs round 3, 3072 blocks for full TLP.
// Per-block partials to DISTINCT addresses; counts only from p==0 blocks.
__global__ __launch_bounds__(256, 8) void k_ce(const float* __restrict__ preds,
                                               const unsigned long long* __restrict__ bitsBG,
                                               const unsigned long long* __restrict__ bitsFG,
                                               float* __restrict__ pf,
                                               float* __restrict__ pbg,
                                               int* __restrict__ pcf,
                                               int* __restrict__ pcb) {
  int tid = blockIdx.x * 256 + threadIdx.x;   // [0, 3*8*32768)
  int g8  = tid & 32767;                      // 8-px group within image
  int pb  = tid >> 15;                        // 0..23
  int b   = pb & 7;
  int p   = pb >> 3;                          // 0..2 (uniform per block)

  int wi = (b << 12) + (g8 >> 3);             // u64 word index
  int sh = (g8 & 7) << 3;                     // byte shift within word
  unsigned nB = (unsigned)(bitsBG[wi] >> sh) & 255u;
  unsigned nF = (unsigned)(bitsFG[wi] >> sh) & 255u;

  const float* pbase = preds + ((size_t)((p * Bsz + b) * 2) << LOG2HW);
  int px = g8 << 3;
  float4 A0a = *(const float4*)&pbase[px];
  float4 A0b = *(const float4*)&pbase[px + 4];
  float4 A1a = *(const float4*)&pbase[HWv + px];
  float4 A1b = *(const float4*)&pbase[HWv + px + 4];

  float d[8] = {A0a.x - A1a.x, A0a.y - A1a.y, A0a.z - A1a.z, A0a.w - A1a.w,
                A0b.x - A1b.x, A0b.y - A1b.y, A0b.z - A1b.z, A0b.w - A1b.w};
  float sfg = 0.f, sbg = 0.f;
  #pragma unroll
  for (int j = 0; j < 8; ++j) {
    float sp = logf(1.f + expf(-fabsf(d[j])));
    bool vfj = (nF >> j) & 1u;
    bool vbj = !((nB >> j) & 1u);
    sfg += vfj ? (fmaxf(d[j], 0.f) + sp) : 0.f;
    sbg += vbj ? (fmaxf(-d[j], 0.f) + sp) : 0.f;
  }
  int cf = __popc(nF);
  int cb = 8 - __popc(nB);

  // block reduction: wave64 shuffle -> LDS -> one partial-write per block
  #pragma unroll
  for (int off = 32; off > 0; off >>= 1) {
    sfg += __shfl_down(sfg, off);
    sbg += __shfl_down(sbg, off);
    cf  += __shfl_down(cf, off);
    cb  += __shfl_down(cb, off);
  }
  __shared__ float lsf[4], lsb[4];
  __shared__ int   lcf[4], lcb[4];
  int wave = threadIdx.x >> 6;
  if ((threadIdx.x & 63) == 0) {
    lsf[wave] = sfg; lsb[wave] = sbg; lcf[wave] = cf; lcb[wave] = cb;
  }
  __syncthreads();
  if (threadIdx.x == 0) {
    pf[blockIdx.x]  = lsf[0] + lsf[1] + lsf[2] + lsf[3];
    pbg[blockIdx.x] = lsb[0] + lsb[1] + lsb[2] + lsb[3];
    if (p == 0) {                       // count each pixel ONCE (p==0 blocks)
      pcf[blockIdx.x] = lcf[0] + lcf[1] + lcf[2] + lcf[3];
      pcb[blockIdx.x] = lcb[0] + lcb[1] + lcb[2] + lcb[3];
    }
  }
}

// Final reduce: 3072x2 float partials + 1024x2 int partials in one block.
__global__ __launch_bounds__(1024) void k_final(const float* __restrict__ pf,
                                                const float* __restrict__ pbg,
                                                const int* __restrict__ pcf,
                                                const int* __restrict__ pcb,
                                                float* __restrict__ out) {
  int t = threadIdx.x;
  double sf = 0.0, sb = 0.0;
  #pragma unroll
  for (int k = 0; k < CEBLK / 1024; ++k) {
    sf += (double)pf[k * 1024 + t];
    sb += (double)pbg[k * 1024 + t];
  }
  int cf = pcf[t];                     // CNTBLK == 1024 exactly
  int cb = pcb[t];
  #pragma unroll
  for (int off = 32; off > 0; off >>= 1) {
    sf += __shfl_down(sf, off);
    sb += __shfl_down(sb, off);
    cf += __shfl_down(cf, off);
    cb += __shfl_down(cb, off);
  }
  __shared__ double dsf[16], dsb[16];
  __shared__ int    icf[16], icb[16];
  int wave = t >> 6;
  if ((t & 63) == 0) { dsf[wave] = sf; dsb[wave] = sb; icf[wave] = cf; icb[wave] = cb; }
  __syncthreads();
  if (t == 0) {
    double tf = 0.0, tb = 0.0; int af_ = 0, ab_ = 0;
    #pragma unroll
    for (int w = 0; w < 16; ++w) { tf += dsf[w]; tb += dsb[w]; af_ += icf[w]; ab_ += icb[w]; }
    double df = af_ > 0 ? (double)af_ : 1.0;
    double db = ab_ > 0 ? (double)ab_ : 1.0;
    out[0] = (float)(tf / df + tb / db);
  }
}

extern "C" void kernel_launch(void* const* d_in, const int* in_sizes, int n_in,
                              void* d_out, int out_size, void* d_ws, size_t ws_size,
                              hipStream_t stream) {
  (void)in_sizes; (void)n_in; (void)out_size; (void)ws_size;
  const float* preds = (const float*)d_in[0];  // [3,8,2,512,512] f32
  const float* cams  = (const float*)d_in[1];  // [8,1,512,512]  f32
  float* out = (float*)d_out;                  // scalar f32

  int* labels = (int*)d_ws;
  int* areasF = labels + NIMG * HWv;
  int* maxa   = areasF + NIMG * HWv;
  double* sums = (double*)(maxa + 16);         // legacy slot (keeps alignment)
  int* counts  = (int*)(sums + 2);
  unsigned long long* bitsBG = (unsigned long long*)(counts + 2);  // 8-aligned
  unsigned long long* bitsFG = bitsBG + Bsz * (HWv / 64);          // 256 KB each
  float* pf  = (float*)(bitsFG + Bsz * (HWv / 64));
  float* pbg = pf + CEBLK;
  int*   pcf = (int*)(pbg + CEBLK);
  int*   pcb = pcf + CNTBLK;
  int*   rootlist = pcb + CNTBLK;              // NTILE*LCAP ints (8 MB)
  int*   rootcnt  = rootlist + NTILE * LCAP;   // NTILE ints

  const int threads = 256;

  k_local  <<<NTILE, threads, 0, stream>>>(cams, labels, areasF, maxa, rootlist, rootcnt);
  k_border <<<NBORD, threads, 0, stream>>>(labels);
  k_flat2  <<<NTILE, threads, 0, stream>>>(labels, rootlist, rootcnt, areasF, maxa);
  k_vmerge <<<NTILE, threads, 0, stream>>>(labels, rootlist, rootcnt, areasF, maxa, bitsBG, bitsFG);
  k_ce     <<<CEBLK, threads, 0, stream>>>(preds, bitsBG, bitsFG, pf, pbg, pcf, pcb);
  k_final  <<<1, 1024, 0, stream>>>(pf, pbg, pcf, pcb, out);
}